// Round 1
// baseline (384.226 us; speedup 1.0000x reference)
//
#include <hip/hip_runtime.h>
#include <math.h>

#define HH 64
#define WW 64
#define CC 256
#define NTOK 4096
#define NHEADS 8
#define HD 32
#define KSZ 7
#define FFD 1024
#define LN_EPS 1e-5f
#define QSCALE 0.17677669529663687f  // 1/sqrt(32)

// ---------------- LayerNorm: one wave (64 lanes) per token ----------------
__global__ void ln_kernel(const float* __restrict__ x, const float* __restrict__ g,
                          const float* __restrict__ b, float* __restrict__ out) {
    int wave = threadIdx.x >> 6;
    int lane = threadIdx.x & 63;
    int tok = blockIdx.x * 4 + wave;
    const float4 v = ((const float4*)(x + tok * CC))[lane];
    float s  = v.x + v.y + v.z + v.w;
    float ss = v.x*v.x + v.y*v.y + v.z*v.z + v.w*v.w;
    #pragma unroll
    for (int o = 32; o > 0; o >>= 1) { s += __shfl_xor(s, o); ss += __shfl_xor(ss, o); }
    float m   = s * (1.0f / CC);
    float var = ss * (1.0f / CC) - m * m;
    float r   = rsqrtf(var + LN_EPS);
    float4 gv = ((const float4*)g)[lane];
    float4 bv = ((const float4*)b)[lane];
    float4 o4;
    o4.x = (v.x - m) * r * gv.x + bv.x;
    o4.y = (v.y - m) * r * gv.y + bv.y;
    o4.z = (v.z - m) * r * gv.z + bv.z;
    o4.w = (v.w - m) * r * gv.w + bv.w;
    ((float4*)(out + tok * CC))[lane] = o4;
}

// ---------------- Generic fp32 GEMM: C = act((A@B + bias)*alpha) + res ----
// A: [M,K] row-major, B: [K,N] row-major. 64x64 tile, BK=16, 256 thr, 4x4/thr.
// ACT: 0=none, 1=exact gelu. ADD_RES: add res[row*N+col].
template<int ACT, bool ADD_RES>
__global__ void gemm_kernel(const float* __restrict__ A, const float* __restrict__ B,
                            const float* __restrict__ bias, const float* __restrict__ res,
                            float* __restrict__ Cm, int M, int N, int Kd, float alpha) {
    __shared__ float As[16][65];
    __shared__ float Bs[16][64];
    const int bn = blockIdx.x * 64;
    const int bm = blockIdx.y * 64;
    const int t  = threadIdx.x;
    const int tx = t & 15;   // col group
    const int ty = t >> 4;   // row group
    float acc[4][4] = {};
    for (int k0 = 0; k0 < Kd; k0 += 16) {
        #pragma unroll
        for (int i = 0; i < 4; i++) {
            int idx = t + i * 256;
            int r = idx >> 4, c = idx & 15;
            As[c][r] = A[(bm + r) * Kd + k0 + c];
        }
        #pragma unroll
        for (int i = 0; i < 4; i++) {
            int idx = t + i * 256;
            int r = idx >> 6, c = idx & 63;
            Bs[r][c] = B[(k0 + r) * N + bn + c];
        }
        __syncthreads();
        #pragma unroll
        for (int kk = 0; kk < 16; kk++) {
            float a0[4], b0[4];
            #pragma unroll
            for (int i = 0; i < 4; i++) a0[i] = As[kk][ty * 4 + i];
            #pragma unroll
            for (int j = 0; j < 4; j++) b0[j] = Bs[kk][tx * 4 + j];
            #pragma unroll
            for (int i = 0; i < 4; i++)
                #pragma unroll
                for (int j = 0; j < 4; j++) acc[i][j] += a0[i] * b0[j];
        }
        __syncthreads();
    }
    #pragma unroll
    for (int i = 0; i < 4; i++) {
        int row = bm + ty * 4 + i;
        #pragma unroll
        for (int j = 0; j < 4; j++) {
            int col = bn + tx * 4 + j;
            float vv = (acc[i][j] + bias[col]) * alpha;
            if (ACT == 1) vv = 0.5f * vv * (1.0f + erff(vv * 0.70710678118654752f));
            if (ADD_RES) vv += res[row * N + col];
            Cm[row * N + col] = vv;
        }
    }
}

// ---------------- Dilated neighborhood attention: wave per (token, head) --
// phase1: lane n<49 computes score_n = q . k_nb[n] + rpb; phase2: wave softmax;
// phase3: lane d<32 computes ctx[d] = sum_n p_n * v_nb[n][d].
__global__ void attn_kernel(const float* __restrict__ q, const float* __restrict__ k,
                            const float* __restrict__ v, const float* __restrict__ rpb,
                            float* __restrict__ ctx) {
    __shared__ float ps[4][64];
    int wave = threadIdx.x >> 6;
    int lane = threadIdx.x & 63;
    int gid  = blockIdx.x * 4 + wave;   // token*8 + head
    int tok  = gid >> 3;
    int head = gid & 7;
    int i = tok >> 6, j = tok & 63;

    // axis indices (L=64, K=7, DIL=2 -> lg=32, start = clamp(g-3, 0, 25))
    int gi = i >> 1, ri = i & 1;
    int gj = j >> 1, rj = j & 1;
    int si = min(max(gi - 3, 0), 25);
    int sj = min(max(gj - 3, 0), 25);

    float score = -1e30f;
    if (lane < 49) {
        int a1 = lane / 7, a2 = lane % 7;
        int ki = (si + a1) * 2 + ri;
        int kj = (sj + a2) * 2 + rj;
        int kt = ki * 64 + kj;
        const float* qp = q + tok * CC + head * HD;
        const float* kp = k + kt * CC + head * HD;
        float s = 0.0f;
        #pragma unroll
        for (int d = 0; d < HD; d += 4) {
            float4 qv = *(const float4*)(qp + d);
            float4 kv = *(const float4*)(kp + d);
            s += qv.x * kv.x + qv.y * kv.y + qv.z * kv.z + qv.w * kv.w;
        }
        int bi = si + a1 - gi + 6;
        int bj = sj + a2 - gj + 6;
        score = s + rpb[(head * 13 + bi) * 13 + bj];
    }
    // wave softmax over the 49 active lanes
    float mx = score;
    #pragma unroll
    for (int o = 32; o > 0; o >>= 1) mx = fmaxf(mx, __shfl_xor(mx, o));
    float p = (lane < 49) ? __expf(score - mx) : 0.0f;
    float sum = p;
    #pragma unroll
    for (int o = 32; o > 0; o >>= 1) sum += __shfl_xor(sum, o);
    p /= sum;
    ps[wave][lane] = p;
    __syncthreads();

    if (lane < HD) {
        const float* vb = v + head * HD + lane;
        float acc = 0.0f;
        #pragma unroll
        for (int a1 = 0; a1 < 7; a1++) {
            int ki = (si + a1) * 2 + ri;
            int rowbase = ki * 64;
            #pragma unroll
            for (int a2 = 0; a2 < 7; a2++) {
                int kj = (sj + a2) * 2 + rj;
                acc += ps[wave][a1 * 7 + a2] * vb[(rowbase + kj) * CC];
            }
        }
        ctx[tok * CC + head * HD + lane] = acc;
    }
}

extern "C" void kernel_launch(void* const* d_in, const int* in_sizes, int n_in,
                              void* d_out, int out_size, void* d_ws, size_t ws_size,
                              hipStream_t stream) {
    const float* x     = (const float*)d_in[0];
    const float* ln1_g = (const float*)d_in[1];
    const float* ln1_b = (const float*)d_in[2];
    const float* wq    = (const float*)d_in[3];
    const float* bq    = (const float*)d_in[4];
    const float* wk    = (const float*)d_in[5];
    const float* bk    = (const float*)d_in[6];
    const float* wv    = (const float*)d_in[7];
    const float* bv    = (const float*)d_in[8];
    const float* rpb   = (const float*)d_in[9];
    const float* wo    = (const float*)d_in[10];
    const float* bo    = (const float*)d_in[11];
    const float* ln2_g = (const float*)d_in[12];
    const float* ln2_b = (const float*)d_in[13];
    const float* w1    = (const float*)d_in[14];
    const float* b1    = (const float*)d_in[15];
    const float* w2    = (const float*)d_in[16];
    const float* b2    = (const float*)d_in[17];

    float* ws   = (float*)d_ws;
    const int SL = NTOK * CC;           // 1048576 floats per activation slab
    float* hs   = ws;                   // slot 0
    float* q    = ws + SL;              // slot 1
    float* k    = ws + 2 * SL;          // slot 2
    float* v    = ws + 3 * SL;          // slot 3
    float* ctx  = hs;                   // reuse slot 0 (hs dead after QKV)
    float* hs2  = q;                    // reuse slot 1 (q dead after attn)
    float* y1   = k;                    // reuse slot 2
    float* gmid = ws + 3 * SL;          // slots 3..6 (v dead after attn) 16MB
    float* out  = (float*)d_out;

    // 1. hs = LN1(x)
    ln_kernel<<<NTOK / 4, 256, 0, stream>>>(x, ln1_g, ln1_b, hs);
    // 2-4. q,k,v  (q pre-scaled)
    gemm_kernel<0, false><<<dim3(CC / 64, NTOK / 64), 256, 0, stream>>>(
        hs, wq, bq, nullptr, q, NTOK, CC, CC, QSCALE);
    gemm_kernel<0, false><<<dim3(CC / 64, NTOK / 64), 256, 0, stream>>>(
        hs, wk, bk, nullptr, k, NTOK, CC, CC, 1.0f);
    gemm_kernel<0, false><<<dim3(CC / 64, NTOK / 64), 256, 0, stream>>>(
        hs, wv, bv, nullptr, v, NTOK, CC, CC, 1.0f);
    // 5. neighborhood attention -> ctx
    attn_kernel<<<NTOK * NHEADS / 4, 256, 0, stream>>>(q, k, v, rpb, ctx);
    // 6. hs2 = x + ctx@wo + bo
    gemm_kernel<0, true><<<dim3(CC / 64, NTOK / 64), 256, 0, stream>>>(
        ctx, wo, bo, x, hs2, NTOK, CC, CC, 1.0f);
    // 7. y1 = LN2(hs2)
    ln_kernel<<<NTOK / 4, 256, 0, stream>>>(hs2, ln2_g, ln2_b, y1);
    // 8. gmid = gelu(y1@w1 + b1)
    gemm_kernel<1, false><<<dim3(FFD / 64, NTOK / 64), 256, 0, stream>>>(
        y1, w1, b1, nullptr, gmid, NTOK, FFD, CC, 1.0f);
    // 9. out = hs2 + gmid@w2 + b2
    gemm_kernel<0, true><<<dim3(CC / 64, NTOK / 64), 256, 0, stream>>>(
        gmid, w2, b2, hs2, out, NTOK, CC, FFD, 1.0f);
}

// Round 2
// 189.661 us; speedup vs baseline: 2.0259x; 2.0259x over previous
//
#include <hip/hip_runtime.h>
#include <math.h>

#define CC 256
#define NTOK 4096
#define NHEADS 8
#define HD 32
#define FFD 1024
#define LN_EPS 1e-5f
#define QSCALE 0.17677669529663687f  // 1/sqrt(32)

typedef __bf16 bf16x8 __attribute__((ext_vector_type(8)));
typedef float f32x4 __attribute__((ext_vector_type(4)));
typedef unsigned short u16x8 __attribute__((ext_vector_type(8)));

__device__ __forceinline__ unsigned short f2bf(float f) {
    unsigned u = __builtin_bit_cast(unsigned, f);
    u += 0x7fff + ((u >> 16) & 1);   // RNE
    return (unsigned short)(u >> 16);
}
__device__ __forceinline__ float bf2f(unsigned short h) {
    unsigned u = ((unsigned)h) << 16;
    return __builtin_bit_cast(float, u);
}
__device__ __forceinline__ void gload16(const unsigned short* g, unsigned short* l) {
    __builtin_amdgcn_global_load_lds(
        (const __attribute__((address_space(1))) unsigned int*)(const void*)g,
        (__attribute__((address_space(3))) unsigned int*)(void*)l, 16, 0, 0);
}

// ---------------- LayerNorm: one wave per token, fp32 in -> bf16 out -------
__global__ void ln_kernel(const float* __restrict__ x, const float* __restrict__ g,
                          const float* __restrict__ b, unsigned short* __restrict__ out) {
    int wave = threadIdx.x >> 6;
    int lane = threadIdx.x & 63;
    int tok = blockIdx.x * 4 + wave;
    const float4 v = ((const float4*)(x + (size_t)tok * CC))[lane];
    float s  = v.x + v.y + v.z + v.w;
    float ss = v.x * v.x + v.y * v.y + v.z * v.z + v.w * v.w;
    #pragma unroll
    for (int o = 32; o > 0; o >>= 1) { s += __shfl_xor(s, o); ss += __shfl_xor(ss, o); }
    float m   = s * (1.0f / CC);
    float var = ss * (1.0f / CC) - m * m;
    float r   = rsqrtf(var + LN_EPS);
    float4 gv = ((const float4*)g)[lane];
    float4 bv = ((const float4*)b)[lane];
    ushort4 o4;
    o4.x = f2bf((v.x - m) * r * gv.x + bv.x);
    o4.y = f2bf((v.y - m) * r * gv.y + bv.y);
    o4.z = f2bf((v.z - m) * r * gv.z + bv.z);
    o4.w = f2bf((v.w - m) * r * gv.w + bv.w);
    ((ushort4*)(out + (size_t)tok * CC))[lane] = o4;
}

// ---------------- Weight transpose+convert: W[K,N] fp32 -> Wt[N,K] bf16 ----
__global__ void transpose_w(const float* __restrict__ W, unsigned short* __restrict__ Wt,
                            int Kd, int N, float scale, int rowoff) {
    __shared__ float tile[64][65];
    int n0 = blockIdx.x * 64, k0 = blockIdx.y * 64;
    int t = threadIdx.x;
    int cc = t & 63, rb = t >> 6;
    #pragma unroll
    for (int i = 0; i < 16; i++) {
        int r = rb + i * 4;
        tile[r][cc] = W[(size_t)(k0 + r) * N + n0 + cc];
    }
    __syncthreads();
    int n = t >> 2;
    #pragma unroll
    for (int i = 0; i < 8; i++) {
        int p = (t & 3) + i * 4;                 // u32 slot (2 bf16)
        unsigned lo = f2bf(tile[2 * p][n] * scale);
        unsigned hi = f2bf(tile[2 * p + 1][n] * scale);
        *(unsigned*)(Wt + (size_t)(rowoff + n0 + n) * Kd + k0 + 2 * p) = lo | (hi << 16);
    }
}

__global__ void fuse_bias(const float* __restrict__ bq, const float* __restrict__ bk,
                          const float* __restrict__ bv, float* __restrict__ bqkv) {
    int t = threadIdx.x;
    bqkv[t]       = bq[t] * QSCALE;
    bqkv[256 + t] = bk[t];
    bqkv[512 + t] = bv[t];
}

// ---------------- bf16 MFMA GEMM (m97 structure): C = act(A@Wt^T + bias)+res
// A [M,K] bf16 row-major, Bt [N,K] bf16 row-major (i.e. W^T). BK=32.
// 4 waves (2x2), wave tile (BM/2)x(BN/2). ACT: 0 none, 1 exact gelu.
template<int BM, int BN, int ACT, bool ADD_RES, bool OUT_BF16>
__global__ __launch_bounds__(256) void mfma_gemm(
    const unsigned short* __restrict__ A, const unsigned short* __restrict__ Bt,
    const float* __restrict__ bias, const float* __restrict__ res,
    void* __restrict__ Cm, int N, int Kd) {
    constexpr int WM = BM / 2, WN = BN / 2;
    constexpr int MF = WM / 16, NF = WN / 16;
    __shared__ unsigned short lds[(BM + BN) * 32];
    unsigned short* Bl = lds + BM * 32;
    const int t = threadIdx.x;
    const int lane = t & 63, w = t >> 6;
    const int wr = w >> 1, wc = w & 1;
    const int bm = blockIdx.y * BM, bn = blockIdx.x * BN;
    const int fr = lane & 15, sq = lane >> 4;
    const int aoff = (wr * WM + fr) * 64 + sq * 16;   // byte offset in A tile
    const int boff = (wc * WN + fr) * 64 + sq * 16;   // byte offset in B tile

    f32x4 acc[MF][NF] = {};
    for (int k0 = 0; k0 < Kd; k0 += 32) {
        #pragma unroll
        for (int i = 0; i < BM / 64; i++) {
            int c = t + i * 256;
            gload16(A + (size_t)(bm + (c >> 2)) * Kd + k0 + (c & 3) * 8, lds + c * 8);
        }
        #pragma unroll
        for (int i = 0; i < BN / 64; i++) {
            int c = t + i * 256;
            gload16(Bt + (size_t)(bn + (c >> 2)) * Kd + k0 + (c & 3) * 8, Bl + c * 8);
        }
        __syncthreads();
        bf16x8 af[MF], bf[NF];
        #pragma unroll
        for (int i = 0; i < MF; i++)
            af[i] = *(const bf16x8*)((const char*)lds + aoff + i * 1024);
        #pragma unroll
        for (int j = 0; j < NF; j++)
            bf[j] = *(const bf16x8*)((const char*)Bl + boff + j * 1024);
        #pragma unroll
        for (int i = 0; i < MF; i++)
            #pragma unroll
            for (int j = 0; j < NF; j++)
                acc[i][j] = __builtin_amdgcn_mfma_f32_16x16x32_bf16(af[i], bf[j], acc[i][j], 0, 0, 0);
        __syncthreads();
    }
    // epilogue: C/D layout col=lane&15, row=(lane>>4)*4+reg  [m89/m91 verified]
    #pragma unroll
    for (int i = 0; i < MF; i++) {
        int row0 = bm + wr * WM + i * 16 + sq * 4;
        #pragma unroll
        for (int j = 0; j < NF; j++) {
            int col = bn + wc * WN + j * 16 + fr;
            float bvv = bias[col];
            #pragma unroll
            for (int r = 0; r < 4; r++) {
                float v = acc[i][j][r] + bvv;
                if constexpr (ACT == 1) v = 0.5f * v * (1.0f + erff(v * 0.70710678118654752f));
                if constexpr (ADD_RES) v += res[(size_t)(row0 + r) * N + col];
                if constexpr (OUT_BF16)
                    ((unsigned short*)Cm)[(size_t)(row0 + r) * N + col] = f2bf(v);
                else
                    ((float*)Cm)[(size_t)(row0 + r) * N + col] = v;
            }
        }
    }
}

// ---------------- Dilated neighborhood attention, bf16 in/out --------------
// qkv [tok][768]: cols 0-255 q (pre-scaled), 256-511 k, 512-767 v.
__global__ void attn_kernel(const unsigned short* __restrict__ qkv,
                            const float* __restrict__ rpb,
                            unsigned short* __restrict__ ctx) {
    __shared__ float ps[4][64];
    int wave = threadIdx.x >> 6;
    int lane = threadIdx.x & 63;
    int gid  = blockIdx.x * 4 + wave;   // token*8 + head
    int tok  = gid >> 3;
    int head = gid & 7;
    int i = tok >> 6, j = tok & 63;
    int gi = i >> 1, ri = i & 1;
    int gj = j >> 1, rj = j & 1;
    int si = min(max(gi - 3, 0), 25);
    int sj = min(max(gj - 3, 0), 25);

    float score = -1e30f;
    if (lane < 49) {
        int a1 = lane / 7, a2 = lane % 7;
        int ki = (si + a1) * 2 + ri;
        int kj = (sj + a2) * 2 + rj;
        int kt = ki * 64 + kj;
        const unsigned short* qp = qkv + (size_t)tok * 768 + head * HD;
        const unsigned short* kp = qkv + (size_t)kt * 768 + 256 + head * HD;
        float s = 0.0f;
        #pragma unroll
        for (int d = 0; d < HD; d += 8) {
            u16x8 qv8 = *(const u16x8*)(qp + d);
            u16x8 kv8 = *(const u16x8*)(kp + d);
            #pragma unroll
            for (int e = 0; e < 8; e++) s += bf2f(qv8[e]) * bf2f(kv8[e]);
        }
        score = s + rpb[(head * 13 + (si + a1 - gi + 6)) * 13 + (sj + a2 - gj + 6)];
    }
    float mx = score;
    #pragma unroll
    for (int o = 32; o > 0; o >>= 1) mx = fmaxf(mx, __shfl_xor(mx, o));
    float p = (lane < 49) ? __expf(score - mx) : 0.0f;
    float sum = p;
    #pragma unroll
    for (int o = 32; o > 0; o >>= 1) sum += __shfl_xor(sum, o);
    p /= sum;
    ps[wave][lane] = p;
    __syncthreads();

    if (lane < HD) {
        const unsigned short* vb = qkv + 512 + head * HD + lane;
        float acc = 0.0f;
        #pragma unroll
        for (int a1 = 0; a1 < 7; a1++) {
            int rowb = ((si + a1) * 2 + ri) * 64;
            #pragma unroll
            for (int a2 = 0; a2 < 7; a2++) {
                int kt = rowb + (sj + a2) * 2 + rj;
                acc += ps[wave][a1 * 7 + a2] * bf2f(vb[(size_t)kt * 768]);
            }
        }
        ctx[(size_t)tok * CC + head * HD + lane] = f2bf(acc);
    }
}

extern "C" void kernel_launch(void* const* d_in, const int* in_sizes, int n_in,
                              void* d_out, int out_size, void* d_ws, size_t ws_size,
                              hipStream_t stream) {
    const float* x     = (const float*)d_in[0];
    const float* ln1_g = (const float*)d_in[1];
    const float* ln1_b = (const float*)d_in[2];
    const float* wq    = (const float*)d_in[3];
    const float* bq    = (const float*)d_in[4];
    const float* wk    = (const float*)d_in[5];
    const float* bk    = (const float*)d_in[6];
    const float* wv    = (const float*)d_in[7];
    const float* bv    = (const float*)d_in[8];
    const float* rpb   = (const float*)d_in[9];
    const float* wo    = (const float*)d_in[10];
    const float* bo    = (const float*)d_in[11];
    const float* ln2_g = (const float*)d_in[12];
    const float* ln2_b = (const float*)d_in[13];
    const float* w1    = (const float*)d_in[14];
    const float* b1    = (const float*)d_in[15];
    const float* w2    = (const float*)d_in[16];
    const float* b2    = (const float*)d_in[17];

    char* wsb = (char*)d_ws;
    unsigned short* hs_bf  = (unsigned short*)(wsb);                    // 2 MB
    unsigned short* qkv_bf = (unsigned short*)(wsb + (2u << 20));       // 6 MB
    unsigned short* ctx_bf = (unsigned short*)(wsb + (8u << 20));       // 2 MB
    float*          hs2    = (float*)(wsb + (10u << 20));               // 4 MB
    unsigned short* y1_bf  = (unsigned short*)(wsb + (14u << 20));      // 2 MB
    unsigned short* gm_bf  = (unsigned short*)(wsb + (16u << 20));      // 8 MB
    unsigned short* wt_qkv = (unsigned short*)(wsb + (24u << 20));      // 768x256
    unsigned short* wo_t   = wt_qkv + 768 * 256;                        // 256x256
    unsigned short* w1_t   = wo_t + 256 * 256;                          // 1024x256
    unsigned short* w2_t   = w1_t + 1024 * 256;                         // 256x1024
    float*          bqkv   = (float*)(w2_t + 256 * 1024);               // 768

    // weight convert + transpose (bf16, W^T layout), QSCALE folded into wq/bq
    transpose_w<<<dim3(4, 4),  256, 0, stream>>>(wq, wt_qkv, 256, 256, QSCALE, 0);
    transpose_w<<<dim3(4, 4),  256, 0, stream>>>(wk, wt_qkv, 256, 256, 1.0f, 256);
    transpose_w<<<dim3(4, 4),  256, 0, stream>>>(wv, wt_qkv, 256, 256, 1.0f, 512);
    transpose_w<<<dim3(4, 4),  256, 0, stream>>>(wo, wo_t, 256, 256, 1.0f, 0);
    transpose_w<<<dim3(16, 4), 256, 0, stream>>>(w1, w1_t, 256, 1024, 1.0f, 0);
    transpose_w<<<dim3(4, 16), 256, 0, stream>>>(w2, w2_t, 1024, 256, 1.0f, 0);
    fuse_bias<<<1, 256, 0, stream>>>(bq, bk, bv, bqkv);

    // 1. hs = LN1(x)  (bf16)
    ln_kernel<<<NTOK / 4, 256, 0, stream>>>(x, ln1_g, ln1_b, hs_bf);
    // 2. fused QKV: [4096,768]
    mfma_gemm<128, 128, 0, false, true><<<dim3(6, 32), 256, 0, stream>>>(
        hs_bf, wt_qkv, bqkv, nullptr, qkv_bf, 768, 256);
    // 3. neighborhood attention
    attn_kernel<<<NTOK * NHEADS / 4, 256, 0, stream>>>(qkv_bf, rpb, ctx_bf);
    // 4. hs2 = x + ctx@wo + bo  (fp32)
    mfma_gemm<64, 64, 0, true, false><<<dim3(4, 64), 256, 0, stream>>>(
        ctx_bf, wo_t, bo, x, hs2, 256, 256);
    // 5. y1 = LN2(hs2)  (bf16)
    ln_kernel<<<NTOK / 4, 256, 0, stream>>>(hs2, ln2_g, ln2_b, y1_bf);
    // 6. gmid = gelu(y1@w1 + b1)  (bf16)
    mfma_gemm<128, 128, 1, false, true><<<dim3(8, 32), 256, 0, stream>>>(
        y1_bf, w1_t, b1, nullptr, gm_bf, 1024, 256);
    // 7. out = hs2 + gmid@w2 + b2  (fp32)
    mfma_gemm<64, 64, 0, true, false><<<dim3(4, 64), 256, 0, stream>>>(
        gm_bf, w2_t, b2, hs2, (float*)d_out, 256, 1024);
}

// Round 3
// 164.669 us; speedup vs baseline: 2.3333x; 1.1518x over previous
//
#include <hip/hip_runtime.h>
#include <math.h>

#define CC 256
#define NTOK 4096
#define NHEADS 8
#define HD 32
#define FFD 1024
#define LN_EPS 1e-5f
#define QSCALE 0.17677669529663687f  // 1/sqrt(32)

typedef __bf16 bf16x8 __attribute__((ext_vector_type(8)));
typedef float f32x4 __attribute__((ext_vector_type(4)));
typedef unsigned short u16x8 __attribute__((ext_vector_type(8)));

__device__ __forceinline__ unsigned short f2bf(float f) {
    unsigned u = __builtin_bit_cast(unsigned, f);
    u += 0x7fff + ((u >> 16) & 1);   // RNE
    return (unsigned short)(u >> 16);
}
__device__ __forceinline__ float bf2f(unsigned short h) {
    unsigned u = ((unsigned)h) << 16;
    return __builtin_bit_cast(float, u);
}
__device__ __forceinline__ void gload16(const unsigned short* g, unsigned short* l) {
    __builtin_amdgcn_global_load_lds(
        (const __attribute__((address_space(1))) unsigned int*)(const void*)g,
        (__attribute__((address_space(3))) unsigned int*)(void*)l, 16, 0, 0);
}

// ---------------- LayerNorm: one wave per token, fp32 in -> bf16 out -------
__global__ void ln_kernel(const float* __restrict__ x, const float* __restrict__ g,
                          const float* __restrict__ b, unsigned short* __restrict__ out) {
    int wave = threadIdx.x >> 6;
    int lane = threadIdx.x & 63;
    int tok = blockIdx.x * 4 + wave;
    const float4 v = ((const float4*)(x + (size_t)tok * CC))[lane];
    float s  = v.x + v.y + v.z + v.w;
    float ss = v.x * v.x + v.y * v.y + v.z * v.z + v.w * v.w;
    #pragma unroll
    for (int o = 32; o > 0; o >>= 1) { s += __shfl_xor(s, o); ss += __shfl_xor(ss, o); }
    float m   = s * (1.0f / CC);
    float var = ss * (1.0f / CC) - m * m;
    float r   = rsqrtf(var + LN_EPS);
    float4 gv = ((const float4*)g)[lane];
    float4 bv = ((const float4*)b)[lane];
    ushort4 o4;
    o4.x = f2bf((v.x - m) * r * gv.x + bv.x);
    o4.y = f2bf((v.y - m) * r * gv.y + bv.y);
    o4.z = f2bf((v.z - m) * r * gv.z + bv.z);
    o4.w = f2bf((v.w - m) * r * gv.w + bv.w);
    ((ushort4*)(out + (size_t)tok * CC))[lane] = o4;
}

// ---------------- Merged setup: all weight transposes + bias fuse ----------
// blocks 0..191: 64x64 transpose tiles; block 192: bias fuse.
__global__ void setup_kernel(const float* __restrict__ wq, const float* __restrict__ wk,
                             const float* __restrict__ wv, const float* __restrict__ wo,
                             const float* __restrict__ w1, const float* __restrict__ w2,
                             const float* __restrict__ bq, const float* __restrict__ bk,
                             const float* __restrict__ bv,
                             unsigned short* __restrict__ wt_qkv, unsigned short* __restrict__ wo_t,
                             unsigned short* __restrict__ w1_t, unsigned short* __restrict__ w2_t,
                             float* __restrict__ bqkv) {
    int id = blockIdx.x;
    int t = threadIdx.x;
    if (id == 192) {
        bqkv[t]       = bq[t] * QSCALE;
        bqkv[256 + t] = bk[t];
        bqkv[512 + t] = bv[t];
        return;
    }
    const float* src; unsigned short* dst;
    int Kd, N, rowoff = 0, bx, by; float scale = 1.0f;
    if (id < 16)       { src = wq; dst = wt_qkv; Kd = 256;  N = 256;  scale = QSCALE; int l = id;       bx = l & 3;  by = l >> 2; }
    else if (id < 32)  { src = wk; dst = wt_qkv; Kd = 256;  N = 256;  rowoff = 256;   int l = id - 16;  bx = l & 3;  by = l >> 2; }
    else if (id < 48)  { src = wv; dst = wt_qkv; Kd = 256;  N = 256;  rowoff = 512;   int l = id - 32;  bx = l & 3;  by = l >> 2; }
    else if (id < 64)  { src = wo; dst = wo_t;   Kd = 256;  N = 256;                  int l = id - 48;  bx = l & 3;  by = l >> 2; }
    else if (id < 128) { src = w1; dst = w1_t;   Kd = 256;  N = 1024;                 int l = id - 64;  bx = l & 15; by = l >> 4; }
    else               { src = w2; dst = w2_t;   Kd = 1024; N = 256;                  int l = id - 128; bx = l & 3;  by = l >> 2; }
    int n0 = bx * 64, k0 = by * 64;
    __shared__ float tile[64][65];
    int cc = t & 63, rb = t >> 6;
    #pragma unroll
    for (int i = 0; i < 16; i++) {
        int r = rb + i * 4;
        tile[r][cc] = src[(size_t)(k0 + r) * N + n0 + cc];
    }
    __syncthreads();
    int n = t >> 2;
    #pragma unroll
    for (int i = 0; i < 8; i++) {
        int p = (t & 3) + i * 4;
        unsigned lo = f2bf(tile[2 * p][n] * scale);
        unsigned hi = f2bf(tile[2 * p + 1][n] * scale);
        *(unsigned*)(dst + (size_t)(rowoff + n0 + n) * Kd + k0 + 2 * p) = lo | (hi << 16);
    }
}

// ---------------- bf16 MFMA GEMM, 2-phase double-buffered ------------------
// A [M,K] bf16, Bt [N,K] bf16 (W^T). BK=32, KD compile-time, 4 waves (2x2).
// One __syncthreads per K-step; stage(t+1) issued right after it so the
// global_load_lds latency hides under ds_read+MFMA of step t.
template<int BM, int BN, int KD, int ACT, bool ADD_RES, bool OUT_BF16>
__global__ __launch_bounds__(256) void mfma_gemm(
    const unsigned short* __restrict__ A, const unsigned short* __restrict__ Bt,
    const float* __restrict__ bias, const float* __restrict__ res,
    void* __restrict__ Cm, int N) {
    constexpr int WM = BM / 2, WN = BN / 2;
    constexpr int MF = WM / 16, NF = WN / 16;
    constexpr int NIT = KD / 32;
    __shared__ unsigned short lds[2][(BM + BN) * 32];
    const int t = threadIdx.x;
    const int lane = t & 63, w = t >> 6;
    const int wr = w >> 1, wc = w & 1;
    const int bm = blockIdx.y * BM, bn = blockIdx.x * BN;
    const int fr = lane & 15, sq = lane >> 4;
    const int aoff = (wr * WM + fr) * 64 + sq * 16;   // byte offset in A tile
    const int boff = (wc * WN + fr) * 64 + sq * 16;   // byte offset in B tile

    auto stage = [&](int it, int buf) {
        unsigned short* La = lds[buf];
        unsigned short* Lb = lds[buf] + BM * 32;
        if (BM * 4 == 256 || t < BM * 4)
            gload16(A + (size_t)(bm + (t >> 2)) * KD + it * 32 + (t & 3) * 8, La + t * 8);
        gload16(Bt + (size_t)(bn + (t >> 2)) * KD + it * 32 + (t & 3) * 8, Lb + t * 8);
    };

    f32x4 acc[MF][NF] = {};
    stage(0, 0);
    #pragma unroll
    for (int it = 0; it < NIT; ++it) {
        const int buf = it & 1;
        __syncthreads();                    // drains stage(it)'s vmcnt
        if (it + 1 < NIT) stage(it + 1, buf ^ 1);
        const char* La = (const char*)lds[buf];
        const char* Lb = (const char*)(lds[buf] + BM * 32);
        bf16x8 af[MF], bfr[NF];
        #pragma unroll
        for (int i = 0; i < MF; i++) af[i] = *(const bf16x8*)(La + aoff + i * 1024);
        #pragma unroll
        for (int j = 0; j < NF; j++) bfr[j] = *(const bf16x8*)(Lb + boff + j * 1024);
        #pragma unroll
        for (int i = 0; i < MF; i++)
            #pragma unroll
            for (int j = 0; j < NF; j++)
                acc[i][j] = __builtin_amdgcn_mfma_f32_16x16x32_bf16(af[i], bfr[j], acc[i][j], 0, 0, 0);
    }
    // epilogue: C/D layout col=lane&15, row=(lane>>4)*4+reg
    #pragma unroll
    for (int i = 0; i < MF; i++) {
        int row0 = bm + wr * WM + i * 16 + sq * 4;
        #pragma unroll
        for (int j = 0; j < NF; j++) {
            int col = bn + wc * WN + j * 16 + fr;
            float bvv = bias[col];
            #pragma unroll
            for (int r = 0; r < 4; r++) {
                float v = acc[i][j][r] + bvv;
                if constexpr (ACT == 1) v = 0.5f * v * (1.0f + erff(v * 0.70710678118654752f));
                if constexpr (ADD_RES) v += res[(size_t)(row0 + r) * N + col];
                if constexpr (OUT_BF16)
                    ((unsigned short*)Cm)[(size_t)(row0 + r) * N + col] = f2bf(v);
                else
                    ((float*)Cm)[(size_t)(row0 + r) * N + col] = v;
            }
        }
    }
}

// ---------------- Dilated neighborhood attention, bf16 in/out --------------
// qkv [tok][768]: 0-255 q (pre-scaled), 256-511 k, 512-767 v. Wave-local:
// no __syncthreads (ps slice is per-wave). PV uses all 64 lanes
// (even/odd neighbor halves), combined via shfl_xor(32).
__global__ void attn_kernel(const unsigned short* __restrict__ qkv,
                            const float* __restrict__ rpb,
                            unsigned short* __restrict__ ctx) {
    __shared__ float ps[4][64];
    int wave = threadIdx.x >> 6;
    int lane = threadIdx.x & 63;
    int gid  = blockIdx.x * 4 + wave;   // token*8 + head
    int tok  = gid >> 3;
    int head = gid & 7;
    int i = tok >> 6, j = tok & 63;
    int gi = i >> 1, ri = i & 1;
    int gj = j >> 1, rj = j & 1;
    int si = min(max(gi - 3, 0), 25);
    int sj = min(max(gj - 3, 0), 25);

    float score = -1e30f;
    if (lane < 49) {
        int a1 = lane / 7, a2 = lane % 7;
        int kt = ((si + a1) * 2 + ri) * 64 + (sj + a2) * 2 + rj;
        const unsigned short* qp = qkv + (size_t)tok * 768 + head * HD;
        const unsigned short* kp = qkv + (size_t)kt * 768 + 256 + head * HD;
        float s = 0.0f;
        #pragma unroll
        for (int d = 0; d < HD; d += 8) {
            u16x8 qv8 = *(const u16x8*)(qp + d);
            u16x8 kv8 = *(const u16x8*)(kp + d);
            #pragma unroll
            for (int e = 0; e < 8; e++) s += bf2f(qv8[e]) * bf2f(kv8[e]);
        }
        score = s + rpb[(head * 13 + (si + a1 - gi + 6)) * 13 + (sj + a2 - gj + 6)];
    }
    float mx = score;
    #pragma unroll
    for (int o = 32; o > 0; o >>= 1) mx = fmaxf(mx, __shfl_xor(mx, o));
    float p = (lane < 49) ? __expf(score - mx) : 0.0f;
    float sum = p;
    #pragma unroll
    for (int o = 32; o > 0; o >>= 1) sum += __shfl_xor(sum, o);
    ps[wave][lane] = p / sum;      // wave-local: ds ordering handles visibility

    int d = lane & 31, half = lane >> 5;
    const unsigned short* vb = qkv + 512 + head * HD + d;
    float acc = 0.0f;
    #pragma unroll
    for (int s = 0; s < 25; ++s) {
        int nb = 2 * s + half;
        if (nb < 49) {
            int a1 = nb / 7, a2 = nb % 7;
            int kt = ((si + a1) * 2 + ri) * 64 + (sj + a2) * 2 + rj;
            acc += ps[wave][nb] * bf2f(vb[(size_t)kt * 768]);
        }
    }
    acc += __shfl_xor(acc, 32);
    if (lane < HD)
        ctx[(size_t)tok * CC + head * HD + lane] = f2bf(acc);
}

extern "C" void kernel_launch(void* const* d_in, const int* in_sizes, int n_in,
                              void* d_out, int out_size, void* d_ws, size_t ws_size,
                              hipStream_t stream) {
    const float* x     = (const float*)d_in[0];
    const float* ln1_g = (const float*)d_in[1];
    const float* ln1_b = (const float*)d_in[2];
    const float* wq    = (const float*)d_in[3];
    const float* bq    = (const float*)d_in[4];
    const float* wk    = (const float*)d_in[5];
    const float* bk    = (const float*)d_in[6];
    const float* wv    = (const float*)d_in[7];
    const float* bv    = (const float*)d_in[8];
    const float* rpb   = (const float*)d_in[9];
    const float* wo    = (const float*)d_in[10];
    const float* bo    = (const float*)d_in[11];
    const float* ln2_g = (const float*)d_in[12];
    const float* ln2_b = (const float*)d_in[13];
    const float* w1    = (const float*)d_in[14];
    const float* b1    = (const float*)d_in[15];
    const float* w2    = (const float*)d_in[16];
    const float* b2    = (const float*)d_in[17];

    char* wsb = (char*)d_ws;
    unsigned short* hs_bf  = (unsigned short*)(wsb);                    // 2 MB
    unsigned short* qkv_bf = (unsigned short*)(wsb + (2u << 20));       // 6 MB
    unsigned short* ctx_bf = (unsigned short*)(wsb + (8u << 20));       // 2 MB
    float*          hs2    = (float*)(wsb + (10u << 20));               // 4 MB
    unsigned short* y1_bf  = (unsigned short*)(wsb + (14u << 20));      // 2 MB
    unsigned short* gm_bf  = (unsigned short*)(wsb + (16u << 20));      // 8 MB
    unsigned short* wt_qkv = (unsigned short*)(wsb + (24u << 20));      // 768x256
    unsigned short* wo_t   = wt_qkv + 768 * 256;                        // 256x256
    unsigned short* w1_t   = wo_t + 256 * 256;                          // 1024x256
    unsigned short* w2_t   = w1_t + 1024 * 256;                         // 256x1024
    float*          bqkv   = (float*)(w2_t + 256 * 1024);               // 768

    // 0. merged weight transpose/convert + bias fuse (1 launch)
    setup_kernel<<<193, 256, 0, stream>>>(wq, wk, wv, wo, w1, w2, bq, bk, bv,
                                          wt_qkv, wo_t, w1_t, w2_t, bqkv);
    // 1. hs = LN1(x)
    ln_kernel<<<NTOK / 4, 256, 0, stream>>>(x, ln1_g, ln1_b, hs_bf);
    // 2. fused QKV: [4096,768] = hs @ [wq|wk|wv]
    mfma_gemm<64, 64, 256, 0, false, true><<<dim3(12, 64), 256, 0, stream>>>(
        hs_bf, wt_qkv, bqkv, nullptr, qkv_bf, 768);
    // 3. neighborhood attention
    attn_kernel<<<NTOK * NHEADS / 4, 256, 0, stream>>>(qkv_bf, rpb, ctx_bf);
    // 4. hs2 = x + ctx@wo + bo  (fp32)
    mfma_gemm<32, 64, 256, 0, true, false><<<dim3(4, 128), 256, 0, stream>>>(
        ctx_bf, wo_t, bo, x, hs2, 256);
    // 5. y1 = LN2(hs2)
    ln_kernel<<<NTOK / 4, 256, 0, stream>>>(hs2, ln2_g, ln2_b, y1_bf);
    // 6. gmid = gelu(y1@w1 + b1)
    mfma_gemm<64, 64, 256, 1, false, true><<<dim3(16, 64), 256, 0, stream>>>(
        y1_bf, w1_t, b1, nullptr, gm_bf, 1024);
    // 7. out = hs2 + gmid@w2 + b2  (fp32)
    mfma_gemm<32, 64, 1024, 0, true, false><<<dim3(4, 128), 256, 0, stream>>>(
        gm_bf, w2_t, b2, hs2, (float*)d_out, 256);
}